// Round 1
// baseline (886.870 us; speedup 1.0000x reference)
//
#include <hip/hip_runtime.h>
#include <hip/hip_bf16.h>
#include <stdint.h>

// NaN-masked euclidean distances via MX-scaled all-fp8 MFMA (unity scales).
//   prepass: X -> xc, xx, p (fp8 e4m3); Y -> m2=-2y, yy, q (fp8 e4m3)
//            stored pre-swizzled (16B-chunk XOR perm within 64B k-group) so main
//            staging is an identity global_load_lds copy.
//   main v2: 256x128 tile, 512 thr (8 waves, 4x2), double-buffered LDS (2x72KB),
//            2-phase pipeline: issue stage(kc+1) -> ds_read(kc) -> setprio MFMA ->
//            single barrier (vmcnt drain covered by ~2200cy compute). XCD swizzle.
//   d = xx*q + p*yy + xc*m2 ; cnt = p*q  (fp8 0/1 products -> exact)
//   out = sqrt(clip(d,0)*D/max(1,cnt)), NaN where cnt==0.
// MFMA floor 29.3us (137.4 GFLOP @ 4686 TF MX ubench).

typedef __bf16 bf16_t;
typedef __attribute__((ext_vector_type(8))) __bf16 bf16x8;
typedef __attribute__((ext_vector_type(4))) float floatx4;
typedef __attribute__((ext_vector_type(16))) float floatx16;
typedef __attribute__((ext_vector_type(8))) int int32x8;

#define NROWS 4096
#define MCOLS 4096
#define DDIM  1024
#define BM 128
#define BN 128
#define BM2 256
#define BN2 128
#define BK 64

// ws layout: 6 fp8 planes x 4 MB (row = 1024 B, pre-swizzled chunks)
#define WS_XX ((uint32_t)0)
#define WS_XC ((uint32_t)(4  << 20))
#define WS_P  ((uint32_t)(8  << 20))
#define WS_YY ((uint32_t)(12 << 20))
#define WS_M2 ((uint32_t)(16 << 20))
#define WS_Q  ((uint32_t)(20 << 20))
#define WS_NEEDED ((size_t)(24 << 20))

// LDS double-buffer layout: per buffer 72KB =
//   A planes (256 rows x 64B): XX @0, XC @16K, P @32K
//   B planes (128 rows x 64B): YY @48K, M2 @56K, Q @64K
#define BUF_STRIDE 73728
#define L2_XX 0
#define L2_XC 16384
#define L2_P  32768
#define L2_YY 49152
#define L2_M2 57344
#define L2_Q  65536

// ---------------- prepass: fp32 -> 6 fp8 planes, pre-swizzled ----------------
__global__ __launch_bounds__(256)
void convert_planes_mx(const float* __restrict__ X, const float* __restrict__ Y,
                       char* __restrict__ ws) {
    int b = blockIdx.x;
    bool isX = (b < 1024);
    const float* src = isX ? X : Y;
    int rb = isX ? b : b - 1024;
    int row = rb * 4 + (threadIdx.x >> 6);
    int l = threadIdx.x & 63;
    int k0 = l << 4;

    const float4* p = (const float4*)(src + (size_t)row * DDIM + k0);
    float v[16];
    #pragma unroll
    for (int i = 0; i < 4; i++) {
        float4 t = p[i];
        v[4*i+0] = t.x; v[4*i+1] = t.y; v[4*i+2] = t.z; v[4*i+3] = t.w;
    }
    float fa[16], fb[16], fm[16];   // fa: xc or -2y ; fb: x^2 or y^2 ; fm: present mask
    #pragma unroll
    for (int i = 0; i < 16; i++) {
        float x = v[i];
        bool miss = __builtin_isnan(x);
        float c = miss ? 0.f : x;
        fb[i] = c * c;
        fa[i] = isX ? c : (-2.f * c);
        fm[i] = miss ? 0.f : 1.f;
    }
    uint32_t da[4], db[4], dm[4];
    #pragma unroll
    for (int i = 0; i < 4; i++) {
        int r = __builtin_amdgcn_cvt_pk_fp8_f32(fa[4*i], fa[4*i+1], 0, 0);
        r     = __builtin_amdgcn_cvt_pk_fp8_f32(fa[4*i+2], fa[4*i+3], r, 1);
        da[i] = (uint32_t)r;
        int s = __builtin_amdgcn_cvt_pk_fp8_f32(fb[4*i], fb[4*i+1], 0, 0);
        s     = __builtin_amdgcn_cvt_pk_fp8_f32(fb[4*i+2], fb[4*i+3], s, 1);
        db[i] = (uint32_t)s;
        int m = __builtin_amdgcn_cvt_pk_fp8_f32(fm[4*i], fm[4*i+1], 0, 0);
        m     = __builtin_amdgcn_cvt_pk_fp8_f32(fm[4*i+2], fm[4*i+3], m, 1);
        dm[i] = (uint32_t)m;
    }
    // 16B chunk swizzle inside each 64B k-group: phys = logical ^ ((row>>1)&3)
    uint32_t off8 = (uint32_t)row * 1024u + (uint32_t)(l >> 2) * 64u
                  + (uint32_t)((((l & 3) ^ ((row >> 1) & 3)) << 4));
    uint4 A = make_uint4(da[0], da[1], da[2], da[3]);
    uint4 B = make_uint4(db[0], db[1], db[2], db[3]);
    uint4 M = make_uint4(dm[0], dm[1], dm[2], dm[3]);
    if (isX) {
        *(uint4*)(ws + WS_XC + off8) = A;
        *(uint4*)(ws + WS_XX + off8) = B;
        *(uint4*)(ws + WS_P  + off8) = M;
    } else {
        *(uint4*)(ws + WS_M2 + off8) = A;
        *(uint4*)(ws + WS_YY + off8) = B;
        *(uint4*)(ws + WS_Q  + off8) = M;
    }
}

// ---------------- main MX MFMA kernel (v2: dbuf 2-phase) ----------------
__device__ __forceinline__ int32x8 ld32B(const char* p0, const char* p1) {
    union { int32x8 v; int4 h[2]; } u;
    u.h[0] = *(const int4*)p0;
    u.h[1] = *(const int4*)p1;
    return u.v;
}

__global__ __launch_bounds__(512, 2)
void nan_euclid_mx2(const char* __restrict__ ws, float* __restrict__ out) {
    __shared__ __align__(16) char ldsb[2 * BUF_STRIDE];   // 144 KiB

    const int tid = threadIdx.x, lane = tid & 63, wid = tid >> 6;
    const int l31 = lane & 31, kh = lane >> 5;
    const int wrow = (wid >> 1) * 64;    // 4 wave-rows: 0,64,128,192
    const int wcol = (wid & 1) * 64;     // 2 wave-cols: 0,64

    // bijective XCD swizzle: 512 blocks = 8 XCDs x 64; then row-major decompose
    const int bid = blockIdx.x;
    const int swz = (bid & 7) * 64 + (bid >> 3);
    const int blockRow = (swz >> 5) * BM2;   // 16 row-blocks of 256
    const int blockCol = (swz & 31) * BN2;   // 32 col-blocks of 128

    // staging: 9 global_load_lds (16B) per thread per kc; identity copy.
    // chunk id ch in [0,4608): A region [0,3072): plane=ch>>10, row=(ch&1023)>>2, cc=ch&3
    //                          B region [3072,4608): plane=(ch-3072)>>9, row/cc analog
    // LDS byte = ch*16 (matches plane bases above).
    uint32_t goff[9];
    #pragma unroll
    for (int t = 0; t < 9; t++) {
        int ch = (wid * 9 + t) * 64 + lane;
        uint32_t base; int rg, cc;
        if (ch < 3072) {
            int pl = ch >> 10, c2 = ch & 1023;
            rg = blockRow + (c2 >> 2); cc = c2 & 3;
            base = (pl == 0) ? WS_XX : (pl == 1) ? WS_XC : WS_P;
        } else {
            int ch2 = ch - 3072;
            int pl = ch2 >> 9, c2 = ch2 & 511;
            rg = blockCol + (c2 >> 2); cc = c2 & 3;
            base = (pl == 0) ? WS_YY : (pl == 1) ? WS_M2 : WS_Q;
        }
        goff[t] = base + (uint32_t)rg * 1024u + (uint32_t)(cc << 4);
    }

    // fragment-read LDS offsets (plane-local). Second 16B chunk is aoff^16
    // (XOR swizzle is bitwise: chunk (2kh+1)^sw == ((2kh)^sw)^1).
    int aoff[2], boff[2];
    #pragma unroll
    for (int tt = 0; tt < 2; tt++) {
        int m = wrow + tt * 32 + l31;
        aoff[tt] = m * 64 + ((((kh * 2)) ^ ((m >> 1) & 3)) << 4);
        int n = wcol + tt * 32 + l31;
        boff[tt] = n * 64 + ((((kh * 2)) ^ ((n >> 1) & 3)) << 4);
    }

    floatx16 acc_d[2][2], acc_c[2][2];
    #pragma unroll
    for (int i = 0; i < 2; i++)
        #pragma unroll
        for (int j = 0; j < 2; j++)
            #pragma unroll
            for (int r = 0; r < 16; r++) { acc_d[i][j][r] = 0.f; acc_c[i][j][r] = 0.f; }

    // prologue: stage kc=0 into buffer 0
    #pragma unroll
    for (int t = 0; t < 9; t++) {
        __builtin_amdgcn_global_load_lds(
            (const __attribute__((address_space(1))) void*)(ws + goff[t]),
            (__attribute__((address_space(3))) void*)(ldsb + (uint32_t)((wid * 9 + t) * 1024)),
            16, 0, 0);
    }
    __syncthreads();

    int cur = 0;
    for (int kc = 0; kc < DDIM / BK; kc++) {
        // phase 1: issue next-tile staging into the other buffer (overlaps compute)
        if (kc < DDIM / BK - 1) {
            char* dst = ldsb + (cur ^ 1) * BUF_STRIDE;
            #pragma unroll
            for (int t = 0; t < 9; t++) {
                __builtin_amdgcn_global_load_lds(
                    (const __attribute__((address_space(1))) void*)(ws + goff[t] + (uint32_t)(kc + 1) * 64u),
                    (__attribute__((address_space(3))) void*)(dst + (uint32_t)((wid * 9 + t) * 1024)),
                    16, 0, 0);
            }
        }

        // phase 2: ds_read current buffer
        const char* buf = ldsb + cur * BUF_STRIDE;
        int32x8 axx[2], axc[2], ap[2], byy[2], bm2[2], bq[2];
        #pragma unroll
        for (int tt = 0; tt < 2; tt++) {
            axx[tt] = ld32B(buf + L2_XX + aoff[tt], buf + L2_XX + (aoff[tt] ^ 16));
            axc[tt] = ld32B(buf + L2_XC + aoff[tt], buf + L2_XC + (aoff[tt] ^ 16));
            ap [tt] = ld32B(buf + L2_P  + aoff[tt], buf + L2_P  + (aoff[tt] ^ 16));
            byy[tt] = ld32B(buf + L2_YY + boff[tt], buf + L2_YY + (boff[tt] ^ 16));
            bm2[tt] = ld32B(buf + L2_M2 + boff[tt], buf + L2_M2 + (boff[tt] ^ 16));
            bq [tt] = ld32B(buf + L2_Q  + boff[tt], buf + L2_Q  + (boff[tt] ^ 16));
        }

        // phase 3: MFMA cluster, chain-major (dep distance 4)
        __builtin_amdgcn_s_setprio(1);
        #pragma unroll
        for (int tm = 0; tm < 2; tm++)
            #pragma unroll
            for (int tn = 0; tn < 2; tn++)
                acc_d[tm][tn] = __builtin_amdgcn_mfma_scale_f32_32x32x64_f8f6f4(
                    axx[tm], bq[tn], acc_d[tm][tn], 0, 0, 0, 0x7f7f7f7f, 0, 0x7f7f7f7f);
        #pragma unroll
        for (int tm = 0; tm < 2; tm++)
            #pragma unroll
            for (int tn = 0; tn < 2; tn++)
                acc_d[tm][tn] = __builtin_amdgcn_mfma_scale_f32_32x32x64_f8f6f4(
                    ap[tm], byy[tn], acc_d[tm][tn], 0, 0, 0, 0x7f7f7f7f, 0, 0x7f7f7f7f);
        #pragma unroll
        for (int tm = 0; tm < 2; tm++)
            #pragma unroll
            for (int tn = 0; tn < 2; tn++)
                acc_d[tm][tn] = __builtin_amdgcn_mfma_scale_f32_32x32x64_f8f6f4(
                    axc[tm], bm2[tn], acc_d[tm][tn], 0, 0, 0, 0x7f7f7f7f, 0, 0x7f7f7f7f);
        #pragma unroll
        for (int tm = 0; tm < 2; tm++)
            #pragma unroll
            for (int tn = 0; tn < 2; tn++)
                acc_c[tm][tn] = __builtin_amdgcn_mfma_scale_f32_32x32x64_f8f6f4(
                    ap[tm], bq[tn], acc_c[tm][tn], 0, 0, 0, 0x7f7f7f7f, 0, 0x7f7f7f7f);
        __builtin_amdgcn_s_setprio(0);

        // single barrier per K-step: compiler's vmcnt(0) drain here is covered by
        // the ~2200cy of ds_read+MFMA since the stage was issued at phase 1.
        __syncthreads();
        cur ^= 1;
    }

    // epilogue; 32x32 C/D layout (m74/m101): col = lane&31, row = (reg&3)+8*(reg>>2)+4*(lane>>5)
    #pragma unroll
    for (int tm = 0; tm < 2; tm++) {
        #pragma unroll
        for (int tn = 0; tn < 2; tn++) {
            int col = blockCol + wcol + tn * 32 + l31;
            #pragma unroll
            for (int r = 0; r < 16; r++) {
                int rowl = (r & 3) + 8 * (r >> 2) + 4 * kh;
                int row = blockRow + wrow + tm * 32 + rowl;
                float d = fmaxf(acc_d[tm][tn][r], 0.f);
                float c = acc_c[tm][tn][r];
                float res = (c < 0.5f) ? __builtin_nanf("")
                                       : __builtin_sqrtf(d * (float)DDIM / c);
                out[(size_t)row * MCOLS + col] = res;
            }
        }
    }
}

// ---------------- fallback: fused single-kernel bf16 (if ws too small) ----------------
#define LDK 40
__global__ __launch_bounds__(256, 2)
void nan_euclid_fused(const float* __restrict__ X, const float* __restrict__ Y,
                      float* __restrict__ out) {
    typedef __attribute__((ext_vector_type(4))) __bf16 bf16x4;
    __shared__ bf16_t s_xx[BM * LDK];
    __shared__ bf16_t s_p [BM * LDK];
    __shared__ bf16_t s_xc[BM * LDK];
    __shared__ bf16_t s_q [BN * LDK];
    __shared__ bf16_t s_yy[BN * LDK];
    __shared__ bf16_t s_m2[BN * LDK];

    const int tid  = threadIdx.x;
    const int lane = tid & 63;
    const int wid  = tid >> 6;
    const int quad = lane >> 4;
    const int r16  = lane & 15;
    const int wrow = (wid >> 1) * 64;
    const int wcol = (wid & 1) * 64;
    const int blockRow = blockIdx.y * BM;
    const int blockCol = blockIdx.x * BN;

    floatx4 acc_d[4][4];
    floatx4 acc_c[4][4];
    #pragma unroll
    for (int i = 0; i < 4; i++)
        #pragma unroll
        for (int j = 0; j < 4; j++)
            #pragma unroll
            for (int r = 0; r < 4; r++) { acc_d[i][j][r] = 0.f; acc_c[i][j][r] = 0.f; }

    for (int kc = 0; kc < DDIM / 32; kc++) {
        const int kbase = kc * 32;
        #pragma unroll
        for (int i = 0; i < 4; i++) {
            int idx = tid + 256 * i;
            int row = idx >> 3;
            int c4  = idx & 7;
            const float4 v = *(const float4*)(X + (size_t)(blockRow + row) * DDIM + kbase + c4 * 4);
            bf16x4 vxc, vxx, vp;
            const float xs[4] = {v.x, v.y, v.z, v.w};
            #pragma unroll
            for (int e = 0; e < 4; e++) {
                float x = xs[e];
                bool miss = __builtin_isnan(x);
                float xc = miss ? 0.f : x;
                vxc[e] = (bf16_t)xc;
                vxx[e] = (bf16_t)(xc * xc);
                vp[e]  = miss ? (bf16_t)0.f : (bf16_t)1.f;
            }
            int off = row * LDK + c4 * 4;
            *(bf16x4*)&s_xc[off] = vxc;
            *(bf16x4*)&s_xx[off] = vxx;
            *(bf16x4*)&s_p [off] = vp;
        }
        #pragma unroll
        for (int i = 0; i < 4; i++) {
            int idx = tid + 256 * i;
            int row = idx >> 3;
            int c4  = idx & 7;
            const float4 v = *(const float4*)(Y + (size_t)(blockCol + row) * DDIM + kbase + c4 * 4);
            bf16x4 vq, vyy, vm2;
            const float ys[4] = {v.x, v.y, v.z, v.w};
            #pragma unroll
            for (int e = 0; e < 4; e++) {
                float y = ys[e];
                bool miss = __builtin_isnan(y);
                float yc = miss ? 0.f : y;
                vq[e]  = miss ? (bf16_t)0.f : (bf16_t)1.f;
                vyy[e] = (bf16_t)(yc * yc);
                vm2[e] = (bf16_t)(-2.f * yc);
            }
            int off = row * LDK + c4 * 4;
            *(bf16x4*)&s_q [off] = vq;
            *(bf16x4*)&s_yy[off] = vyy;
            *(bf16x4*)&s_m2[off] = vm2;
        }
        __syncthreads();
        bf16x8 bq[4], byy[4], bm2[4];
        #pragma unroll
        for (int tn = 0; tn < 4; tn++) {
            int off = (wcol + tn * 16 + r16) * LDK + quad * 8;
            bq[tn]  = *(const bf16x8*)&s_q [off];
            byy[tn] = *(const bf16x8*)&s_yy[off];
            bm2[tn] = *(const bf16x8*)&s_m2[off];
        }
        #pragma unroll
        for (int tm = 0; tm < 4; tm++) {
            int off = (wrow + tm * 16 + r16) * LDK + quad * 8;
            bf16x8 axx = *(const bf16x8*)&s_xx[off];
            bf16x8 ap  = *(const bf16x8*)&s_p [off];
            bf16x8 axc = *(const bf16x8*)&s_xc[off];
            #pragma unroll
            for (int tn = 0; tn < 4; tn++) {
                acc_d[tm][tn] = __builtin_amdgcn_mfma_f32_16x16x32_bf16(axx, bq[tn],  acc_d[tm][tn], 0, 0, 0);
                acc_d[tm][tn] = __builtin_amdgcn_mfma_f32_16x16x32_bf16(ap,  byy[tn], acc_d[tm][tn], 0, 0, 0);
                acc_d[tm][tn] = __builtin_amdgcn_mfma_f32_16x16x32_bf16(axc, bm2[tn], acc_d[tm][tn], 0, 0, 0);
                acc_c[tm][tn] = __builtin_amdgcn_mfma_f32_16x16x32_bf16(ap,  bq[tn],  acc_c[tm][tn], 0, 0, 0);
            }
        }
        __syncthreads();
    }
    #pragma unroll
    for (int tm = 0; tm < 4; tm++) {
        #pragma unroll
        for (int tn = 0; tn < 4; tn++) {
            int col = blockCol + wcol + tn * 16 + r16;
            #pragma unroll
            for (int r = 0; r < 4; r++) {
                int row = blockRow + wrow + tm * 16 + quad * 4 + r;
                float d = acc_d[tm][tn][r];
                float c = acc_c[tm][tn][r];
                d = fmaxf(d, 0.f);
                float res = (c < 0.5f) ? __builtin_nanf("")
                                       : __builtin_sqrtf(d * (float)DDIM / c);
                out[(size_t)row * MCOLS + col] = res;
            }
        }
    }
}

extern "C" void kernel_launch(void* const* d_in, const int* in_sizes, int n_in,
                              void* d_out, int out_size, void* d_ws, size_t ws_size,
                              hipStream_t stream) {
    const float* X = (const float*)d_in[0];
    const float* Y = (const float*)d_in[1];
    float* out = (float*)d_out;

    if (ws_size >= WS_NEEDED) {
        char* ws = (char*)d_ws;
        convert_planes_mx<<<dim3(2048), dim3(256), 0, stream>>>(X, Y, ws);
        // 512 blocks: 16 row-blocks (BM2=256) x 32 col-blocks (BN2=128)
        nan_euclid_mx2<<<dim3(512), dim3(512), 0, stream>>>(ws, out);
    } else {
        dim3 grid(MCOLS / BN, NROWS / BM);
        nan_euclid_fused<<<grid, dim3(256), 0, stream>>>(X, Y, out);
    }
}

// Round 2
// 873.235 us; speedup vs baseline: 1.0156x; 1.0156x over previous
//
#include <hip/hip_runtime.h>
#include <hip/hip_bf16.h>
#include <stdint.h>

// NaN-masked euclidean distances via MX-scaled all-fp8 MFMA (unity scales).
//   prepass: X -> xc, xx, p (fp8 e4m3); Y -> m2=-2y, yy, q (fp8 e4m3)
//            stored pre-swizzled (16B-chunk XOR perm within 64B k-group) so main
//            staging is an identity global_load_lds copy.
//   main v3: 256x128 tile, 512 thr (8 waves, 4x2), double-buffered LDS (2x72KB),
//            2-phase pipeline: issue stage(kc+1) -> B-frags -> per-tm {A-frags, MFMA}
//            -> single barrier. Per-tm A loads cap arch VGPR at ~110 (<=128 cap at
//            2 waves/SIMD) -- R1's all-frags-resident version spilled 1.2GB scratch.
//   d = xx*q + p*yy + xc*m2 ; cnt = p*q  (fp8 0/1 products -> exact)
//   out = sqrt(clip(d,0)*D/max(1,cnt)), NaN where cnt==0.
// MFMA floor 29.3us (137.4 GFLOP @ 4686 TF MX ubench); LDS-read pipe floor ~40us.

typedef __bf16 bf16_t;
typedef __attribute__((ext_vector_type(8))) __bf16 bf16x8;
typedef __attribute__((ext_vector_type(4))) float floatx4;
typedef __attribute__((ext_vector_type(16))) float floatx16;
typedef __attribute__((ext_vector_type(8))) int int32x8;

#define NROWS 4096
#define MCOLS 4096
#define DDIM  1024
#define BM 128
#define BN 128
#define BM2 256
#define BN2 128
#define BK 64

// ws layout: 6 fp8 planes x 4 MB (row = 1024 B, pre-swizzled chunks)
#define WS_XX ((uint32_t)0)
#define WS_XC ((uint32_t)(4  << 20))
#define WS_P  ((uint32_t)(8  << 20))
#define WS_YY ((uint32_t)(12 << 20))
#define WS_M2 ((uint32_t)(16 << 20))
#define WS_Q  ((uint32_t)(20 << 20))
#define WS_NEEDED ((size_t)(24 << 20))

// LDS double-buffer layout: per buffer 72KB =
//   A planes (256 rows x 64B): XX @0, XC @16K, P @32K
//   B planes (128 rows x 64B): YY @48K, M2 @56K, Q @64K
#define BUF_STRIDE 73728
#define L2_XX 0
#define L2_XC 16384
#define L2_P  32768
#define L2_YY 49152
#define L2_M2 57344
#define L2_Q  65536

// ---------------- prepass: fp32 -> 6 fp8 planes, pre-swizzled ----------------
__global__ __launch_bounds__(256)
void convert_planes_mx(const float* __restrict__ X, const float* __restrict__ Y,
                       char* __restrict__ ws) {
    int b = blockIdx.x;
    bool isX = (b < 1024);
    const float* src = isX ? X : Y;
    int rb = isX ? b : b - 1024;
    int row = rb * 4 + (threadIdx.x >> 6);
    int l = threadIdx.x & 63;
    int k0 = l << 4;

    const float4* p = (const float4*)(src + (size_t)row * DDIM + k0);
    float v[16];
    #pragma unroll
    for (int i = 0; i < 4; i++) {
        float4 t = p[i];
        v[4*i+0] = t.x; v[4*i+1] = t.y; v[4*i+2] = t.z; v[4*i+3] = t.w;
    }
    float fa[16], fb[16], fm[16];   // fa: xc or -2y ; fb: x^2 or y^2 ; fm: present mask
    #pragma unroll
    for (int i = 0; i < 16; i++) {
        float x = v[i];
        bool miss = __builtin_isnan(x);
        float c = miss ? 0.f : x;
        fb[i] = c * c;
        fa[i] = isX ? c : (-2.f * c);
        fm[i] = miss ? 0.f : 1.f;
    }
    uint32_t da[4], db[4], dm[4];
    #pragma unroll
    for (int i = 0; i < 4; i++) {
        int r = __builtin_amdgcn_cvt_pk_fp8_f32(fa[4*i], fa[4*i+1], 0, 0);
        r     = __builtin_amdgcn_cvt_pk_fp8_f32(fa[4*i+2], fa[4*i+3], r, 1);
        da[i] = (uint32_t)r;
        int s = __builtin_amdgcn_cvt_pk_fp8_f32(fb[4*i], fb[4*i+1], 0, 0);
        s     = __builtin_amdgcn_cvt_pk_fp8_f32(fb[4*i+2], fb[4*i+3], s, 1);
        db[i] = (uint32_t)s;
        int m = __builtin_amdgcn_cvt_pk_fp8_f32(fm[4*i], fm[4*i+1], 0, 0);
        m     = __builtin_amdgcn_cvt_pk_fp8_f32(fm[4*i+2], fm[4*i+3], m, 1);
        dm[i] = (uint32_t)m;
    }
    // 16B chunk swizzle inside each 64B k-group: phys = logical ^ ((row>>1)&3)
    uint32_t off8 = (uint32_t)row * 1024u + (uint32_t)(l >> 2) * 64u
                  + (uint32_t)((((l & 3) ^ ((row >> 1) & 3)) << 4));
    uint4 A = make_uint4(da[0], da[1], da[2], da[3]);
    uint4 B = make_uint4(db[0], db[1], db[2], db[3]);
    uint4 M = make_uint4(dm[0], dm[1], dm[2], dm[3]);
    if (isX) {
        *(uint4*)(ws + WS_XC + off8) = A;
        *(uint4*)(ws + WS_XX + off8) = B;
        *(uint4*)(ws + WS_P  + off8) = M;
    } else {
        *(uint4*)(ws + WS_M2 + off8) = A;
        *(uint4*)(ws + WS_YY + off8) = B;
        *(uint4*)(ws + WS_Q  + off8) = M;
    }
}

// ---------------- main MX MFMA kernel (v3: dbuf 2-phase, low-pressure) ----------------
__device__ __forceinline__ int32x8 ld32B(const char* p0, const char* p1) {
    union { int32x8 v; int4 h[2]; } u;
    u.h[0] = *(const int4*)p0;
    u.h[1] = *(const int4*)p1;
    return u.v;
}

__global__ __launch_bounds__(512, 2)
void nan_euclid_mx2(const char* __restrict__ ws, float* __restrict__ out) {
    __shared__ __align__(16) char ldsb[2 * BUF_STRIDE];   // 144 KiB

    const int tid = threadIdx.x, lane = tid & 63, wid = tid >> 6;
    const int l31 = lane & 31, kh = lane >> 5;
    const int wrow = (wid >> 1) * 64;    // 4 wave-rows: 0,64,128,192
    const int wcol = (wid & 1) * 64;     // 2 wave-cols: 0,64

    // bijective XCD swizzle: 512 blocks = 8 XCDs x 64; then row-major decompose
    const int bid = blockIdx.x;
    const int swz = (bid & 7) * 64 + (bid >> 3);
    const int blockRow = (swz >> 5) * BM2;   // 16 row-blocks of 256
    const int blockCol = (swz & 31) * BN2;   // 32 col-blocks of 128

    // staging: 9 global_load_lds (16B) per thread per kc; identity copy.
    // chunk id ch in [0,4608): A region [0,3072): plane=ch>>10, row=(ch&1023)>>2, cc=ch&3
    //                          B region [3072,4608): plane=(ch-3072)>>9, row/cc analog
    // LDS byte = ch*16 (matches plane bases above).
    uint32_t goff[9];
    #pragma unroll
    for (int t = 0; t < 9; t++) {
        int ch = (wid * 9 + t) * 64 + lane;
        uint32_t base; int rg, cc;
        if (ch < 3072) {
            int pl = ch >> 10, c2 = ch & 1023;
            rg = blockRow + (c2 >> 2); cc = c2 & 3;
            base = (pl == 0) ? WS_XX : (pl == 1) ? WS_XC : WS_P;
        } else {
            int ch2 = ch - 3072;
            int pl = ch2 >> 9, c2 = ch2 & 511;
            rg = blockCol + (c2 >> 2); cc = c2 & 3;
            base = (pl == 0) ? WS_YY : (pl == 1) ? WS_M2 : WS_Q;
        }
        goff[t] = base + (uint32_t)rg * 1024u + (uint32_t)(cc << 4);
    }

    // fragment-read LDS offsets (plane-local). Second 16B chunk is off^16
    // (XOR swizzle is bitwise: chunk (2kh+1)^sw == ((2kh)^sw)^1).
    int aoff[2], boff[2];
    #pragma unroll
    for (int tt = 0; tt < 2; tt++) {
        int m = wrow + tt * 32 + l31;
        aoff[tt] = m * 64 + ((((kh * 2)) ^ ((m >> 1) & 3)) << 4);
        int n = wcol + tt * 32 + l31;
        boff[tt] = n * 64 + ((((kh * 2)) ^ ((n >> 1) & 3)) << 4);
    }

    floatx16 acc_d[2][2], acc_c[2][2];
    #pragma unroll
    for (int i = 0; i < 2; i++)
        #pragma unroll
        for (int j = 0; j < 2; j++)
            #pragma unroll
            for (int r = 0; r < 16; r++) { acc_d[i][j][r] = 0.f; acc_c[i][j][r] = 0.f; }

    // prologue: stage kc=0 into buffer 0
    #pragma unroll
    for (int t = 0; t < 9; t++) {
        __builtin_amdgcn_global_load_lds(
            (const __attribute__((address_space(1))) void*)(ws + goff[t]),
            (__attribute__((address_space(3))) void*)(ldsb + (uint32_t)((wid * 9 + t) * 1024)),
            16, 0, 0);
    }
    __syncthreads();

    int cur = 0;
    for (int kc = 0; kc < DDIM / BK; kc++) {
        // phase 1: issue next-tile staging into the other buffer (overlaps compute)
        if (kc < DDIM / BK - 1) {
            char* dst = ldsb + (cur ^ 1) * BUF_STRIDE;
            #pragma unroll
            for (int t = 0; t < 9; t++) {
                __builtin_amdgcn_global_load_lds(
                    (const __attribute__((address_space(1))) void*)(ws + goff[t] + (uint32_t)(kc + 1) * 64u),
                    (__attribute__((address_space(3))) void*)(dst + (uint32_t)((wid * 9 + t) * 1024)),
                    16, 0, 0);
            }
        }

        // phase 2: B fragments resident (48 VGPRs)
        const char* buf = ldsb + cur * BUF_STRIDE;
        int32x8 byy[2], bm2[2], bq[2];
        #pragma unroll
        for (int tt = 0; tt < 2; tt++) {
            byy[tt] = ld32B(buf + L2_YY + boff[tt], buf + L2_YY + (boff[tt] ^ 16));
            bm2[tt] = ld32B(buf + L2_M2 + boff[tt], buf + L2_M2 + (boff[tt] ^ 16));
            bq [tt] = ld32B(buf + L2_Q  + boff[tt], buf + L2_Q  + (boff[tt] ^ 16));
        }

        // phase 3: per-tm A fragments (24 VGPRs, reused) + MFMA cluster.
        // sched_barrier(0) between tm groups keeps the scheduler from hoisting
        // tm=1's ds_reads over tm=0's MFMAs (which would re-inflate pressure).
        __builtin_amdgcn_s_setprio(1);
        #pragma unroll
        for (int tm = 0; tm < 2; tm++) {
            int32x8 axx = ld32B(buf + L2_XX + aoff[tm], buf + L2_XX + (aoff[tm] ^ 16));
            int32x8 axc = ld32B(buf + L2_XC + aoff[tm], buf + L2_XC + (aoff[tm] ^ 16));
            int32x8 ap  = ld32B(buf + L2_P  + aoff[tm], buf + L2_P  + (aoff[tm] ^ 16));
            #pragma unroll
            for (int tn = 0; tn < 2; tn++)
                acc_d[tm][tn] = __builtin_amdgcn_mfma_scale_f32_32x32x64_f8f6f4(
                    axx, bq[tn], acc_d[tm][tn], 0, 0, 0, 0x7f7f7f7f, 0, 0x7f7f7f7f);
            #pragma unroll
            for (int tn = 0; tn < 2; tn++)
                acc_d[tm][tn] = __builtin_amdgcn_mfma_scale_f32_32x32x64_f8f6f4(
                    ap, byy[tn], acc_d[tm][tn], 0, 0, 0, 0x7f7f7f7f, 0, 0x7f7f7f7f);
            #pragma unroll
            for (int tn = 0; tn < 2; tn++)
                acc_d[tm][tn] = __builtin_amdgcn_mfma_scale_f32_32x32x64_f8f6f4(
                    axc, bm2[tn], acc_d[tm][tn], 0, 0, 0, 0x7f7f7f7f, 0, 0x7f7f7f7f);
            #pragma unroll
            for (int tn = 0; tn < 2; tn++)
                acc_c[tm][tn] = __builtin_amdgcn_mfma_scale_f32_32x32x64_f8f6f4(
                    ap, bq[tn], acc_c[tm][tn], 0, 0, 0, 0x7f7f7f7f, 0, 0x7f7f7f7f);
            __builtin_amdgcn_sched_barrier(0);
        }
        __builtin_amdgcn_s_setprio(0);

        // single barrier per K-step: compiler's vmcnt(0) drain here is covered by
        // the ds_read+MFMA work since the stage was issued at phase 1.
        __syncthreads();
        cur ^= 1;
    }

    // epilogue; 32x32 C/D layout (m74/m101): col = lane&31, row = (reg&3)+8*(reg>>2)+4*(lane>>5)
    #pragma unroll
    for (int tm = 0; tm < 2; tm++) {
        #pragma unroll
        for (int tn = 0; tn < 2; tn++) {
            int col = blockCol + wcol + tn * 32 + l31;
            #pragma unroll
            for (int r = 0; r < 16; r++) {
                int rowl = (r & 3) + 8 * (r >> 2) + 4 * kh;
                int row = blockRow + wrow + tm * 32 + rowl;
                float d = fmaxf(acc_d[tm][tn][r], 0.f);
                float c = acc_c[tm][tn][r];
                float res = (c < 0.5f) ? __builtin_nanf("")
                                       : __builtin_sqrtf(d * (float)DDIM / c);
                out[(size_t)row * MCOLS + col] = res;
            }
        }
    }
}

// ---------------- fallback: fused single-kernel bf16 (if ws too small) ----------------
#define LDK 40
__global__ __launch_bounds__(256, 2)
void nan_euclid_fused(const float* __restrict__ X, const float* __restrict__ Y,
                      float* __restrict__ out) {
    typedef __attribute__((ext_vector_type(4))) __bf16 bf16x4;
    __shared__ bf16_t s_xx[BM * LDK];
    __shared__ bf16_t s_p [BM * LDK];
    __shared__ bf16_t s_xc[BM * LDK];
    __shared__ bf16_t s_q [BN * LDK];
    __shared__ bf16_t s_yy[BN * LDK];
    __shared__ bf16_t s_m2[BN * LDK];

    const int tid  = threadIdx.x;
    const int lane = tid & 63;
    const int wid  = tid >> 6;
    const int quad = lane >> 4;
    const int r16  = lane & 15;
    const int wrow = (wid >> 1) * 64;
    const int wcol = (wid & 1) * 64;
    const int blockRow = blockIdx.y * BM;
    const int blockCol = blockIdx.x * BN;

    floatx4 acc_d[4][4];
    floatx4 acc_c[4][4];
    #pragma unroll
    for (int i = 0; i < 4; i++)
        #pragma unroll
        for (int j = 0; j < 4; j++)
            #pragma unroll
            for (int r = 0; r < 4; r++) { acc_d[i][j][r] = 0.f; acc_c[i][j][r] = 0.f; }

    for (int kc = 0; kc < DDIM / 32; kc++) {
        const int kbase = kc * 32;
        #pragma unroll
        for (int i = 0; i < 4; i++) {
            int idx = tid + 256 * i;
            int row = idx >> 3;
            int c4  = idx & 7;
            const float4 v = *(const float4*)(X + (size_t)(blockRow + row) * DDIM + kbase + c4 * 4);
            bf16x4 vxc, vxx, vp;
            const float xs[4] = {v.x, v.y, v.z, v.w};
            #pragma unroll
            for (int e = 0; e < 4; e++) {
                float x = xs[e];
                bool miss = __builtin_isnan(x);
                float xc = miss ? 0.f : x;
                vxc[e] = (bf16_t)xc;
                vxx[e] = (bf16_t)(xc * xc);
                vp[e]  = miss ? (bf16_t)0.f : (bf16_t)1.f;
            }
            int off = row * LDK + c4 * 4;
            *(bf16x4*)&s_xc[off] = vxc;
            *(bf16x4*)&s_xx[off] = vxx;
            *(bf16x4*)&s_p [off] = vp;
        }
        #pragma unroll
        for (int i = 0; i < 4; i++) {
            int idx = tid + 256 * i;
            int row = idx >> 3;
            int c4  = idx & 7;
            const float4 v = *(const float4*)(Y + (size_t)(blockCol + row) * DDIM + kbase + c4 * 4);
            bf16x4 vq, vyy, vm2;
            const float ys[4] = {v.x, v.y, v.z, v.w};
            #pragma unroll
            for (int e = 0; e < 4; e++) {
                float y = ys[e];
                bool miss = __builtin_isnan(y);
                float yc = miss ? 0.f : y;
                vq[e]  = miss ? (bf16_t)0.f : (bf16_t)1.f;
                vyy[e] = (bf16_t)(yc * yc);
                vm2[e] = (bf16_t)(-2.f * yc);
            }
            int off = row * LDK + c4 * 4;
            *(bf16x4*)&s_q [off] = vq;
            *(bf16x4*)&s_yy[off] = vyy;
            *(bf16x4*)&s_m2[off] = vm2;
        }
        __syncthreads();
        bf16x8 bq[4], byy[4], bm2[4];
        #pragma unroll
        for (int tn = 0; tn < 4; tn++) {
            int off = (wcol + tn * 16 + r16) * LDK + quad * 8;
            bq[tn]  = *(const bf16x8*)&s_q [off];
            byy[tn] = *(const bf16x8*)&s_yy[off];
            bm2[tn] = *(const bf16x8*)&s_m2[off];
        }
        #pragma unroll
        for (int tm = 0; tm < 4; tm++) {
            int off = (wrow + tm * 16 + r16) * LDK + quad * 8;
            bf16x8 axx = *(const bf16x8*)&s_xx[off];
            bf16x8 ap  = *(const bf16x8*)&s_p [off];
            bf16x8 axc = *(const bf16x8*)&s_xc[off];
            #pragma unroll
            for (int tn = 0; tn < 4; tn++) {
                acc_d[tm][tn] = __builtin_amdgcn_mfma_f32_16x16x32_bf16(axx, bq[tn],  acc_d[tm][tn], 0, 0, 0);
                acc_d[tm][tn] = __builtin_amdgcn_mfma_f32_16x16x32_bf16(ap,  byy[tn], acc_d[tm][tn], 0, 0, 0);
                acc_d[tm][tn] = __builtin_amdgcn_mfma_f32_16x16x32_bf16(axc, bm2[tn], acc_d[tm][tn], 0, 0, 0);
                acc_c[tm][tn] = __builtin_amdgcn_mfma_f32_16x16x32_bf16(ap,  bq[tn],  acc_c[tm][tn], 0, 0, 0);
            }
        }
        __syncthreads();
    }
    #pragma unroll
    for (int tm = 0; tm < 4; tm++) {
        #pragma unroll
        for (int tn = 0; tn < 4; tn++) {
            int col = blockCol + wcol + tn * 16 + r16;
            #pragma unroll
            for (int r = 0; r < 4; r++) {
                int row = blockRow + wrow + tm * 16 + quad * 4 + r;
                float d = acc_d[tm][tn][r];
                float c = acc_c[tm][tn][r];
                d = fmaxf(d, 0.f);
                float res = (c < 0.5f) ? __builtin_nanf("")
                                       : __builtin_sqrtf(d * (float)DDIM / c);
                out[(size_t)row * MCOLS + col] = res;
            }
        }
    }
}

extern "C" void kernel_launch(void* const* d_in, const int* in_sizes, int n_in,
                              void* d_out, int out_size, void* d_ws, size_t ws_size,
                              hipStream_t stream) {
    const float* X = (const float*)d_in[0];
    const float* Y = (const float*)d_in[1];
    float* out = (float*)d_out;

    if (ws_size >= WS_NEEDED) {
        char* ws = (char*)d_ws;
        convert_planes_mx<<<dim3(2048), dim3(256), 0, stream>>>(X, Y, ws);
        // 512 blocks: 16 row-blocks (BM2=256) x 32 col-blocks (BN2=128)
        nan_euclid_mx2<<<dim3(512), dim3(512), 0, stream>>>(ws, out);
    } else {
        dim3 grid(MCOLS / BN, NROWS / BM);
        nan_euclid_fused<<<grid, dim3(256), 0, stream>>>(X, Y, out);
    }
}

// Round 3
// 218.432 us; speedup vs baseline: 4.0602x; 3.9977x over previous
//
#include <hip/hip_runtime.h>
#include <hip/hip_bf16.h>
#include <stdint.h>

// NaN-masked euclidean distances via MX-scaled all-fp8 MFMA (unity scales).
//   prepass v2: 1 thread / 4 elems, fully-coalesced float4 loads, dword stores
//               into pre-swizzled fp8 planes (16B-chunk XOR perm per 64B k-group).
//   main v4:   EXACT R0 geometry (128x128 tile, 256 thr, 4 waves 2x2, VGPR 104,
//              no spill) + double-buffered LDS (2x48KB) + stage-early + single
//              barrier per K-step (T3 minimum-2-phase). kc-loop unrolled x2 so
//              buffer select is compile-time. XCD-swizzled 1D grid (1024%8==0).
//   d = xx*q + p*yy + xc*m2 ; cnt = p*q  (fp8 0/1 products -> exact)
//   out = sqrt(clip(d,0)*D/max(1,cnt)), NaN where cnt==0.
// MFMA floor 29.3us; staging floor ~48KB/K-step/CU from L2/L3.

typedef __bf16 bf16_t;
typedef __attribute__((ext_vector_type(8))) __bf16 bf16x8;
typedef __attribute__((ext_vector_type(4))) float floatx4;
typedef __attribute__((ext_vector_type(16))) float floatx16;
typedef __attribute__((ext_vector_type(8))) int int32x8;

#define NROWS 4096
#define MCOLS 4096
#define DDIM  1024
#define BM 128
#define BN 128
#define BK 64

// ws layout: 6 fp8 planes x 4 MB (row = 1024 B, pre-swizzled chunks)
#define WS_XX ((uint32_t)0)
#define WS_XC ((uint32_t)(4  << 20))
#define WS_P  ((uint32_t)(8  << 20))
#define WS_YY ((uint32_t)(12 << 20))
#define WS_M2 ((uint32_t)(16 << 20))
#define WS_Q  ((uint32_t)(20 << 20))
#define WS_NEEDED ((size_t)(24 << 20))

// LDS plane bases within one 48KB buffer: 6 planes x 8192 B ([128 rows x 64 B])
#define L_XX 0
#define L_XC 8192
#define L_P  16384
#define L_YY 24576
#define L_M2 32768
#define L_Q  40960
#define BUFSZ 49152

// ---------------- prepass v2: fp32 -> 6 fp8 planes, pre-swizzled ----------------
// 8192 blocks x 256 thr; 1 row per block; 4 elems per thread.
__global__ __launch_bounds__(256)
void convert_planes_mx(const float* __restrict__ X, const float* __restrict__ Y,
                       char* __restrict__ ws) {
    int b = blockIdx.x;
    bool isX = (b < 4096);
    const float* src = isX ? X : Y;
    int row = isX ? b : b - 4096;
    int l = threadIdx.x;             // 0..255, elems [4l, 4l+4)

    float4 t = *(const float4*)(src + (size_t)row * DDIM + l * 4);
    float v[4] = {t.x, t.y, t.z, t.w};
    float fa[4], fb[4], fm[4];       // fa: xc or -2y ; fb: c^2 ; fm: present
    #pragma unroll
    for (int i = 0; i < 4; i++) {
        float x = v[i];
        bool miss = __builtin_isnan(x);
        float c = miss ? 0.f : x;
        fb[i] = c * c;
        fa[i] = isX ? c : (-2.f * c);
        fm[i] = miss ? 0.f : 1.f;
    }
    int r = __builtin_amdgcn_cvt_pk_fp8_f32(fa[0], fa[1], 0, 0);
    r     = __builtin_amdgcn_cvt_pk_fp8_f32(fa[2], fa[3], r, 1);
    int s = __builtin_amdgcn_cvt_pk_fp8_f32(fb[0], fb[1], 0, 0);
    s     = __builtin_amdgcn_cvt_pk_fp8_f32(fb[2], fb[3], s, 1);
    int m = __builtin_amdgcn_cvt_pk_fp8_f32(fm[0], fm[1], 0, 0);
    m     = __builtin_amdgcn_cvt_pk_fp8_f32(fm[2], fm[3], m, 1);

    // byte pos logical = 4l; 64B group g=l>>4; 16B chunk c=(l>>2)&3 -> c^sw; byte (l&3)*4
    uint32_t sw = ((uint32_t)row >> 1) & 3u;
    uint32_t off = (uint32_t)row * 1024u + (uint32_t)((l >> 4) << 6)
                 + (((((uint32_t)l >> 2) & 3u) ^ sw) << 4) + (uint32_t)((l & 3) << 2);
    if (isX) {
        *(uint32_t*)(ws + WS_XC + off) = (uint32_t)r;
        *(uint32_t*)(ws + WS_XX + off) = (uint32_t)s;
        *(uint32_t*)(ws + WS_P  + off) = (uint32_t)m;
    } else {
        *(uint32_t*)(ws + WS_M2 + off) = (uint32_t)r;
        *(uint32_t*)(ws + WS_YY + off) = (uint32_t)s;
        *(uint32_t*)(ws + WS_Q  + off) = (uint32_t)m;
    }
}

// ---------------- main MX MFMA kernel (v4: R0 geometry + dbuf 2-phase) ----------------
__device__ __forceinline__ int32x8 ld32B(const char* p0, const char* p1) {
    union { int32x8 v; int4 h[2]; } u;
    u.h[0] = *(const int4*)p0;
    u.h[1] = *(const int4*)p1;
    return u.v;
}

__global__ __launch_bounds__(256, 2)
void nan_euclid_mx(const char* __restrict__ ws, float* __restrict__ out) {
    __shared__ __align__(16) char ldsb[2 * BUFSZ];   // 96 KiB double buffer

    const int tid = threadIdx.x, lane = tid & 63, wid = tid >> 6;
    const int l31 = lane & 31, kh = lane >> 5;
    const int wrow = (wid >> 1) * 64, wcol = (wid & 1) * 64;

    // bijective XCD swizzle over 1024 blocks (1024 % 8 == 0)
    const int bid = blockIdx.x;
    const int swz = (bid & 7) * 128 + (bid >> 3);
    const int blockRow = (swz >> 5) * BM;   // 32 row-blocks
    const int blockCol = (swz & 31) * BN;   // 32 col-blocks

    // staging: 12 global_load_lds (16B) per thread per kc; identity copy (ws pre-swizzled)
    // chunk id ch in [0,3072): plane = ch>>9, c2 = ch&511, row = c2>>2, cc = c2&3.
    // LDS byte = ch*16 (dest base (wid*12+t)*1024, HW adds lane*16).
    uint32_t goff[12];
    #pragma unroll
    for (int t = 0; t < 12; t++) {
        int ch = (wid * 12 + t) * 64 + lane;
        int pl = ch >> 9;
        int c2 = ch & 511;
        int row = c2 >> 2, cc = c2 & 3;
        int rg = (pl < 3 ? blockRow : blockCol) + row;
        uint32_t base = (pl == 0) ? WS_XX : (pl == 1) ? WS_XC : (pl == 2) ? WS_P
                      : (pl == 3) ? WS_YY : (pl == 4) ? WS_M2 : WS_Q;
        goff[t] = base + (uint32_t)rg * 1024u + (uint32_t)(cc << 4);
    }

    // fragment-read LDS offsets (plane-local); second 16B chunk is off^16
    // (XOR swizzle is bitwise: chunk (2kh+1)^sw == ((2kh)^sw)^1, 2kh even).
    int aoff[2], boff[2];
    #pragma unroll
    for (int tt = 0; tt < 2; tt++) {
        int m = wrow + tt * 32 + l31;
        aoff[tt] = m * 64 + ((((kh * 2)) ^ ((m >> 1) & 3)) << 4);
        int n = wcol + tt * 32 + l31;
        boff[tt] = n * 64 + ((((kh * 2)) ^ ((n >> 1) & 3)) << 4);
    }

    floatx16 acc_d[2][2], acc_c[2][2];
    #pragma unroll
    for (int i = 0; i < 2; i++)
        #pragma unroll
        for (int j = 0; j < 2; j++)
            #pragma unroll
            for (int r = 0; r < 16; r++) { acc_d[i][j][r] = 0.f; acc_c[i][j][r] = 0.f; }

    // prologue: stage kc=0 into buffer 0
    #pragma unroll
    for (int t = 0; t < 12; t++) {
        __builtin_amdgcn_global_load_lds(
            (const __attribute__((address_space(1))) void*)(ws + goff[t]),
            (__attribute__((address_space(3))) void*)(ldsb + (uint32_t)((wid * 12 + t) * 1024)),
            16, 0, 0);
    }
    __syncthreads();

    // one K-step: stage NKC into buffer NXTB, compute from buffer CURB, one barrier.
    // (compiler emits s_waitcnt vmcnt(0) before s_barrier -> stage(NKC) landed; and
    //  all waves are done reading CURB... stage into NXTB never races readers.)
#define KSTEP(CURB, NXTB, NKC)                                                     \
    do {                                                                           \
        if ((NKC) < DDIM / BK) {                                                   \
            _Pragma("unroll")                                                      \
            for (int t = 0; t < 12; t++) {                                         \
                __builtin_amdgcn_global_load_lds(                                  \
                    (const __attribute__((address_space(1))) void*)(               \
                        ws + goff[t] + (uint32_t)(NKC) * 64u),                     \
                    (__attribute__((address_space(3))) void*)(                     \
                        ldsb + (NXTB) + (uint32_t)((wid * 12 + t) * 1024)),        \
                    16, 0, 0);                                                     \
            }                                                                      \
        }                                                                          \
        const char* buf = ldsb + (CURB);                                           \
        int32x8 axx[2], axc[2], ap[2], byy[2], bm2[2], bq[2];                      \
        _Pragma("unroll")                                                          \
        for (int tt = 0; tt < 2; tt++) {                                           \
            axx[tt] = ld32B(buf + L_XX + aoff[tt], buf + L_XX + (aoff[tt] ^ 16));  \
            axc[tt] = ld32B(buf + L_XC + aoff[tt], buf + L_XC + (aoff[tt] ^ 16));  \
            ap [tt] = ld32B(buf + L_P  + aoff[tt], buf + L_P  + (aoff[tt] ^ 16));  \
            byy[tt] = ld32B(buf + L_YY + boff[tt], buf + L_YY + (boff[tt] ^ 16));  \
            bm2[tt] = ld32B(buf + L_M2 + boff[tt], buf + L_M2 + (boff[tt] ^ 16));  \
            bq [tt] = ld32B(buf + L_Q  + boff[tt], buf + L_Q  + (boff[tt] ^ 16));  \
        }                                                                          \
        _Pragma("unroll")                                                          \
        for (int tm = 0; tm < 2; tm++)                                             \
            _Pragma("unroll")                                                      \
            for (int tn = 0; tn < 2; tn++)                                         \
                acc_d[tm][tn] = __builtin_amdgcn_mfma_scale_f32_32x32x64_f8f6f4(   \
                    axx[tm], bq[tn], acc_d[tm][tn], 0, 0, 0, 0x7f7f7f7f, 0, 0x7f7f7f7f); \
        _Pragma("unroll")                                                          \
        for (int tm = 0; tm < 2; tm++)                                             \
            _Pragma("unroll")                                                      \
            for (int tn = 0; tn < 2; tn++)                                         \
                acc_d[tm][tn] = __builtin_amdgcn_mfma_scale_f32_32x32x64_f8f6f4(   \
                    ap[tm], byy[tn], acc_d[tm][tn], 0, 0, 0, 0x7f7f7f7f, 0, 0x7f7f7f7f); \
        _Pragma("unroll")                                                          \
        for (int tm = 0; tm < 2; tm++)                                             \
            _Pragma("unroll")                                                      \
            for (int tn = 0; tn < 2; tn++)                                         \
                acc_d[tm][tn] = __builtin_amdgcn_mfma_scale_f32_32x32x64_f8f6f4(   \
                    axc[tm], bm2[tn], acc_d[tm][tn], 0, 0, 0, 0x7f7f7f7f, 0, 0x7f7f7f7f); \
        _Pragma("unroll")                                                          \
        for (int tm = 0; tm < 2; tm++)                                             \
            _Pragma("unroll")                                                      \
            for (int tn = 0; tn < 2; tn++)                                         \
                acc_c[tm][tn] = __builtin_amdgcn_mfma_scale_f32_32x32x64_f8f6f4(   \
                    ap[tm], bq[tn], acc_c[tm][tn], 0, 0, 0, 0x7f7f7f7f, 0, 0x7f7f7f7f); \
        __syncthreads();                                                           \
    } while (0)

    // kc-loop unrolled x2: buffer select compile-time constant
    for (int kc2 = 0; kc2 < DDIM / BK / 2; kc2++) {
        KSTEP(0,     BUFSZ, 2 * kc2 + 1);
        KSTEP(BUFSZ, 0,     2 * kc2 + 2);
    }
#undef KSTEP

    // epilogue; 32x32 C/D layout (m74/m101): col = lane&31, row = (reg&3)+8*(reg>>2)+4*(lane>>5)
    #pragma unroll
    for (int tm = 0; tm < 2; tm++) {
        #pragma unroll
        for (int tn = 0; tn < 2; tn++) {
            int col = blockCol + wcol + tn * 32 + l31;
            #pragma unroll
            for (int r = 0; r < 16; r++) {
                int rowl = (r & 3) + 8 * (r >> 2) + 4 * kh;
                int row = blockRow + wrow + tm * 32 + rowl;
                float d = fmaxf(acc_d[tm][tn][r], 0.f);
                float c = acc_c[tm][tn][r];
                float res = (c < 0.5f) ? __builtin_nanf("")
                                       : __builtin_sqrtf(d * (float)DDIM / c);
                out[(size_t)row * MCOLS + col] = res;
            }
        }
    }
}

// ---------------- fallback: fused single-kernel bf16 (if ws too small) ----------------
#define LDK 40
__global__ __launch_bounds__(256, 2)
void nan_euclid_fused(const float* __restrict__ X, const float* __restrict__ Y,
                      float* __restrict__ out) {
    typedef __attribute__((ext_vector_type(4))) __bf16 bf16x4;
    __shared__ bf16_t s_xx[BM * LDK];
    __shared__ bf16_t s_p [BM * LDK];
    __shared__ bf16_t s_xc[BM * LDK];
    __shared__ bf16_t s_q [BN * LDK];
    __shared__ bf16_t s_yy[BN * LDK];
    __shared__ bf16_t s_m2[BN * LDK];

    const int tid  = threadIdx.x;
    const int lane = tid & 63;
    const int wid  = tid >> 6;
    const int quad = lane >> 4;
    const int r16  = lane & 15;
    const int wrow = (wid >> 1) * 64;
    const int wcol = (wid & 1) * 64;
    const int blockRow = blockIdx.y * BM;
    const int blockCol = blockIdx.x * BN;

    floatx4 acc_d[4][4];
    floatx4 acc_c[4][4];
    #pragma unroll
    for (int i = 0; i < 4; i++)
        #pragma unroll
        for (int j = 0; j < 4; j++)
            #pragma unroll
            for (int r = 0; r < 4; r++) { acc_d[i][j][r] = 0.f; acc_c[i][j][r] = 0.f; }

    for (int kc = 0; kc < DDIM / 32; kc++) {
        const int kbase = kc * 32;
        #pragma unroll
        for (int i = 0; i < 4; i++) {
            int idx = tid + 256 * i;
            int row = idx >> 3;
            int c4  = idx & 7;
            const float4 v = *(const float4*)(X + (size_t)(blockRow + row) * DDIM + kbase + c4 * 4);
            bf16x4 vxc, vxx, vp;
            const float xs[4] = {v.x, v.y, v.z, v.w};
            #pragma unroll
            for (int e = 0; e < 4; e++) {
                float x = xs[e];
                bool miss = __builtin_isnan(x);
                float xc = miss ? 0.f : x;
                vxc[e] = (bf16_t)xc;
                vxx[e] = (bf16_t)(xc * xc);
                vp[e]  = miss ? (bf16_t)0.f : (bf16_t)1.f;
            }
            int off = row * LDK + c4 * 4;
            *(bf16x4*)&s_xc[off] = vxc;
            *(bf16x4*)&s_xx[off] = vxx;
            *(bf16x4*)&s_p [off] = vp;
        }
        #pragma unroll
        for (int i = 0; i < 4; i++) {
            int idx = tid + 256 * i;
            int row = idx >> 3;
            int c4  = idx & 7;
            const float4 v = *(const float4*)(Y + (size_t)(blockCol + row) * DDIM + kbase + c4 * 4);
            bf16x4 vq, vyy, vm2;
            const float ys[4] = {v.x, v.y, v.z, v.w};
            #pragma unroll
            for (int e = 0; e < 4; e++) {
                float y = ys[e];
                bool miss = __builtin_isnan(y);
                float yc = miss ? 0.f : y;
                vq[e]  = miss ? (bf16_t)0.f : (bf16_t)1.f;
                vyy[e] = (bf16_t)(yc * yc);
                vm2[e] = (bf16_t)(-2.f * yc);
            }
            int off = row * LDK + c4 * 4;
            *(bf16x4*)&s_q [off] = vq;
            *(bf16x4*)&s_yy[off] = vyy;
            *(bf16x4*)&s_m2[off] = vm2;
        }
        __syncthreads();
        bf16x8 bq[4], byy[4], bm2[4];
        #pragma unroll
        for (int tn = 0; tn < 4; tn++) {
            int off = (wcol + tn * 16 + r16) * LDK + quad * 8;
            bq[tn]  = *(const bf16x8*)&s_q [off];
            byy[tn] = *(const bf16x8*)&s_yy[off];
            bm2[tn] = *(const bf16x8*)&s_m2[off];
        }
        #pragma unroll
        for (int tm = 0; tm < 4; tm++) {
            int off = (wrow + tm * 16 + r16) * LDK + quad * 8;
            bf16x8 axx = *(const bf16x8*)&s_xx[off];
            bf16x8 ap  = *(const bf16x8*)&s_p [off];
            bf16x8 axc = *(const bf16x8*)&s_xc[off];
            #pragma unroll
            for (int tn = 0; tn < 4; tn++) {
                acc_d[tm][tn] = __builtin_amdgcn_mfma_f32_16x16x32_bf16(axx, bq[tn],  acc_d[tm][tn], 0, 0, 0);
                acc_d[tm][tn] = __builtin_amdgcn_mfma_f32_16x16x32_bf16(ap,  byy[tn], acc_d[tm][tn], 0, 0, 0);
                acc_d[tm][tn] = __builtin_amdgcn_mfma_f32_16x16x32_bf16(axc, bm2[tn], acc_d[tm][tn], 0, 0, 0);
                acc_c[tm][tn] = __builtin_amdgcn_mfma_f32_16x16x32_bf16(ap,  bq[tn],  acc_c[tm][tn], 0, 0, 0);
            }
        }
        __syncthreads();
    }
    #pragma unroll
    for (int tm = 0; tm < 4; tm++) {
        #pragma unroll
        for (int tn = 0; tn < 4; tn++) {
            int col = blockCol + wcol + tn * 16 + r16;
            #pragma unroll
            for (int r = 0; r < 4; r++) {
                int row = blockRow + wrow + tm * 16 + quad * 4 + r;
                float d = acc_d[tm][tn][r];
                float c = acc_c[tm][tn][r];
                d = fmaxf(d, 0.f);
                float res = (c < 0.5f) ? __builtin_nanf("")
                                       : __builtin_sqrtf(d * (float)DDIM / c);
                out[(size_t)row * MCOLS + col] = res;
            }
        }
    }
}

extern "C" void kernel_launch(void* const* d_in, const int* in_sizes, int n_in,
                              void* d_out, int out_size, void* d_ws, size_t ws_size,
                              hipStream_t stream) {
    const float* X = (const float*)d_in[0];
    const float* Y = (const float*)d_in[1];
    float* out = (float*)d_out;

    if (ws_size >= WS_NEEDED) {
        char* ws = (char*)d_ws;
        convert_planes_mx<<<dim3(8192), dim3(256), 0, stream>>>(X, Y, ws);
        nan_euclid_mx<<<dim3(1024), dim3(256), 0, stream>>>(ws, out);
    } else {
        dim3 grid(MCOLS / BN, NROWS / BM);
        nan_euclid_fused<<<grid, dim3(256), 0, stream>>>(X, Y, out);
    }
}

// Round 4
// 198.802 us; speedup vs baseline: 4.4611x; 1.0987x over previous
//
#include <hip/hip_runtime.h>
#include <hip/hip_bf16.h>
#include <stdint.h>

// NaN-masked euclidean distances via MX-scaled all-fp8 MFMA (unity scales).
//   prepass: X -> xc, xx, p (fp8 e4m3); Y -> m2=-2y, yy, q (fp8 e4m3)
//            INTERLEAVED ws layout: [row][plane][1KB], row-stride 3KB (R4: tests
//            whether the ~75us non-main time is plane-scatter locality).
//            Pre-swizzled 16B chunks (XOR perm per 64B k-group) so main staging
//            is an identity global_load_lds copy.
//   main v5: EXACT R0 structure (128x128 tile, 256 thr, 4 waves 2x2, single
//            48KB LDS buffer, 2 barriers/K-step, 2D grid) + s_setprio around
//            MFMA cluster. R1-R3 lesson: AGPR=128 floor caps us at 2 waves/SIMD;
//            any scheme costing VGPR (>128) or LDS (>80KB) drops to 1 block/CU
//            and loses the TLP doing the latency hiding.
//   d = xx*q + p*yy + xc*m2 ; cnt = p*q  (fp8 0/1 products -> exact)
//   out = sqrt(clip(d,0)*D/max(1,cnt)), NaN where cnt==0.
// Floors: MFMA 29.3us (per-SIMD 68.7cy/inst), LDS reads 31-41us.

typedef __bf16 bf16_t;
typedef __attribute__((ext_vector_type(8))) __bf16 bf16x8;
typedef __attribute__((ext_vector_type(4))) float floatx4;
typedef __attribute__((ext_vector_type(16))) float floatx16;
typedef __attribute__((ext_vector_type(8))) int int32x8;

#define NROWS 4096
#define MCOLS 4096
#define DDIM  1024
#define BM 128
#define BN 128
#define BK 64

// ws layout (interleaved): X region @0: 4096 rows x 3KB ([row][plane][1KB]);
// Y region @12MB: same. Plane order: X: XX,XC,P ; Y: YY,M2,Q.
#define WS_YBASE ((uint32_t)(12 << 20))
#define WS_NEEDED ((size_t)(24 << 20))

// LDS plane bases: 6 planes x 8192 B ([128 rows x 64 B])
#define L_XX 0
#define L_XC 8192
#define L_P  16384
#define L_YY 24576
#define L_M2 32768
#define L_Q  40960

// ---------------- prepass: fp32 -> 6 fp8 planes, interleaved + pre-swizzled ----------------
// 8192 blocks x 256 thr; 1 row per block; 4 elems per thread; fully coalesced loads.
__global__ __launch_bounds__(256)
void convert_planes_mx(const float* __restrict__ X, const float* __restrict__ Y,
                       char* __restrict__ ws) {
    int b = blockIdx.x;
    bool isX = (b < 4096);
    const float* src = isX ? X : Y;
    int row = isX ? b : b - 4096;
    int l = threadIdx.x;             // 0..255, elems [4l, 4l+4)

    float4 t = *(const float4*)(src + (size_t)row * DDIM + l * 4);
    float v[4] = {t.x, t.y, t.z, t.w};
    float fa[4], fb[4], fm[4];       // fa: xc or -2y ; fb: c^2 ; fm: present
    #pragma unroll
    for (int i = 0; i < 4; i++) {
        float x = v[i];
        bool miss = __builtin_isnan(x);
        float c = miss ? 0.f : x;
        fb[i] = c * c;
        fa[i] = isX ? c : (-2.f * c);
        fm[i] = miss ? 0.f : 1.f;
    }
    int r = __builtin_amdgcn_cvt_pk_fp8_f32(fa[0], fa[1], 0, 0);
    r     = __builtin_amdgcn_cvt_pk_fp8_f32(fa[2], fa[3], r, 1);
    int s = __builtin_amdgcn_cvt_pk_fp8_f32(fb[0], fb[1], 0, 0);
    s     = __builtin_amdgcn_cvt_pk_fp8_f32(fb[2], fb[3], s, 1);
    int m = __builtin_amdgcn_cvt_pk_fp8_f32(fm[0], fm[1], 0, 0);
    m     = __builtin_amdgcn_cvt_pk_fp8_f32(fm[2], fm[3], m, 1);

    // within-plane byte offset: 64B group g=l>>4; 16B chunk ((l>>2)&3)^sw; byte (l&3)*4
    uint32_t sw = ((uint32_t)row >> 1) & 3u;
    uint32_t off = (uint32_t)((l >> 4) << 6)
                 + (((((uint32_t)l >> 2) & 3u) ^ sw) << 4) + (uint32_t)((l & 3) << 2);
    uint32_t base = (isX ? 0u : WS_YBASE) + (uint32_t)row * 3072u;
    // plane 0: XX or YY (squared); plane 1: XC or M2; plane 2: P or Q
    *(uint32_t*)(ws + base +    0u + off) = (uint32_t)s;
    *(uint32_t*)(ws + base + 1024u + off) = (uint32_t)r;
    *(uint32_t*)(ws + base + 2048u + off) = (uint32_t)m;
}

// ---------------- main MX MFMA kernel (v5: R0 structure + setprio) ----------------
__device__ __forceinline__ int32x8 ld32B(const char* p0, const char* p1) {
    union { int32x8 v; int4 h[2]; } u;
    u.h[0] = *(const int4*)p0;
    u.h[1] = *(const int4*)p1;
    return u.v;
}

__global__ __launch_bounds__(256, 2)
void nan_euclid_mx(const char* __restrict__ ws, float* __restrict__ out) {
    __shared__ __align__(16) char ldsb[49152];

    const int tid = threadIdx.x, lane = tid & 63, wid = tid >> 6;
    const int l31 = lane & 31, kh = lane >> 5;
    const int wrow = (wid >> 1) * 64, wcol = (wid & 1) * 64;
    const int blockRow = blockIdx.y * BM, blockCol = blockIdx.x * BN;

    // staging: 12 global_load_lds (16B) per thread per kc; identity copy.
    // chunk id ch in [0,3072): pl = ch>>9 (XX,XC,P,YY,M2,Q), c2 = ch&511,
    // row = c2>>2, cc = c2&3. LDS byte = ch*16 -> plane-contiguous 8KB regions.
    uint32_t goff[12];
    #pragma unroll
    for (int t = 0; t < 12; t++) {
        int ch = (wid * 12 + t) * 64 + lane;
        int pl = ch >> 9;
        int c2 = ch & 511;
        int row = c2 >> 2, cc = c2 & 3;
        bool isA = (pl < 3);
        int rg = (isA ? blockRow : blockCol) + row;
        int pl_loc = isA ? pl : pl - 3;
        goff[t] = (isA ? 0u : WS_YBASE) + (uint32_t)rg * 3072u
                + (uint32_t)pl_loc * 1024u + (uint32_t)(cc << 4);
    }

    // fragment-read LDS offsets (plane-local); second 16B chunk is off^16
    // (XOR swizzle is bitwise: chunk (2kh+1)^sw == ((2kh)^sw)^1, 2kh even).
    int aoff[2], boff[2];
    #pragma unroll
    for (int tt = 0; tt < 2; tt++) {
        int m = wrow + tt * 32 + l31;
        aoff[tt] = m * 64 + ((((kh * 2)) ^ ((m >> 1) & 3)) << 4);
        int n = wcol + tt * 32 + l31;
        boff[tt] = n * 64 + ((((kh * 2)) ^ ((n >> 1) & 3)) << 4);
    }

    floatx16 acc_d[2][2], acc_c[2][2];
    #pragma unroll
    for (int i = 0; i < 2; i++)
        #pragma unroll
        for (int j = 0; j < 2; j++)
            #pragma unroll
            for (int r = 0; r < 16; r++) { acc_d[i][j][r] = 0.f; acc_c[i][j][r] = 0.f; }

    for (int kc = 0; kc < DDIM / BK; kc++) {
        #pragma unroll
        for (int t = 0; t < 12; t++) {
            __builtin_amdgcn_global_load_lds(
                (const __attribute__((address_space(1))) void*)(ws + goff[t] + (uint32_t)kc * 64u),
                (__attribute__((address_space(3))) void*)(ldsb + (uint32_t)((wid * 12 + t) * 1024)),
                16, 0, 0);
        }
        __syncthreads();

        int32x8 axx[2], axc[2], ap[2], byy[2], bm2[2], bq[2];
        #pragma unroll
        for (int tt = 0; tt < 2; tt++) {
            axx[tt] = ld32B(ldsb + L_XX + aoff[tt], ldsb + L_XX + (aoff[tt] ^ 16));
            axc[tt] = ld32B(ldsb + L_XC + aoff[tt], ldsb + L_XC + (aoff[tt] ^ 16));
            ap [tt] = ld32B(ldsb + L_P  + aoff[tt], ldsb + L_P  + (aoff[tt] ^ 16));
            byy[tt] = ld32B(ldsb + L_YY + boff[tt], ldsb + L_YY + (boff[tt] ^ 16));
            bm2[tt] = ld32B(ldsb + L_M2 + boff[tt], ldsb + L_M2 + (boff[tt] ^ 16));
            bq [tt] = ld32B(ldsb + L_Q  + boff[tt], ldsb + L_Q  + (boff[tt] ^ 16));
        }

        // chain-major order: dependency distance 4 insts per accumulator
        __builtin_amdgcn_s_setprio(1);
        #pragma unroll
        for (int tm = 0; tm < 2; tm++)
            #pragma unroll
            for (int tn = 0; tn < 2; tn++)
                acc_d[tm][tn] = __builtin_amdgcn_mfma_scale_f32_32x32x64_f8f6f4(
                    axx[tm], bq[tn], acc_d[tm][tn], 0, 0, 0, 0x7f7f7f7f, 0, 0x7f7f7f7f);
        #pragma unroll
        for (int tm = 0; tm < 2; tm++)
            #pragma unroll
            for (int tn = 0; tn < 2; tn++)
                acc_d[tm][tn] = __builtin_amdgcn_mfma_scale_f32_32x32x64_f8f6f4(
                    ap[tm], byy[tn], acc_d[tm][tn], 0, 0, 0, 0x7f7f7f7f, 0, 0x7f7f7f7f);
        #pragma unroll
        for (int tm = 0; tm < 2; tm++)
            #pragma unroll
            for (int tn = 0; tn < 2; tn++)
                acc_d[tm][tn] = __builtin_amdgcn_mfma_scale_f32_32x32x64_f8f6f4(
                    axc[tm], bm2[tn], acc_d[tm][tn], 0, 0, 0, 0x7f7f7f7f, 0, 0x7f7f7f7f);
        #pragma unroll
        for (int tm = 0; tm < 2; tm++)
            #pragma unroll
            for (int tn = 0; tn < 2; tn++)
                acc_c[tm][tn] = __builtin_amdgcn_mfma_scale_f32_32x32x64_f8f6f4(
                    ap[tm], bq[tn], acc_c[tm][tn], 0, 0, 0, 0x7f7f7f7f, 0, 0x7f7f7f7f);
        __builtin_amdgcn_s_setprio(0);

        __syncthreads();
    }

    // epilogue; 32x32 C/D layout (m74/m101): col = lane&31, row = (reg&3)+8*(reg>>2)+4*(lane>>5)
    #pragma unroll
    for (int tm = 0; tm < 2; tm++) {
        #pragma unroll
        for (int tn = 0; tn < 2; tn++) {
            int col = blockCol + wcol + tn * 32 + l31;
            #pragma unroll
            for (int r = 0; r < 16; r++) {
                int rowl = (r & 3) + 8 * (r >> 2) + 4 * kh;
                int row = blockRow + wrow + tm * 32 + rowl;
                float d = fmaxf(acc_d[tm][tn][r], 0.f);
                float c = acc_c[tm][tn][r];
                float res = (c < 0.5f) ? __builtin_nanf("")
                                       : __builtin_sqrtf(d * (float)DDIM / c);
                out[(size_t)row * MCOLS + col] = res;
            }
        }
    }
}

// ---------------- fallback: fused single-kernel bf16 (if ws too small) ----------------
#define LDK 40
__global__ __launch_bounds__(256, 2)
void nan_euclid_fused(const float* __restrict__ X, const float* __restrict__ Y,
                      float* __restrict__ out) {
    typedef __attribute__((ext_vector_type(4))) __bf16 bf16x4;
    __shared__ bf16_t s_xx[BM * LDK];
    __shared__ bf16_t s_p [BM * LDK];
    __shared__ bf16_t s_xc[BM * LDK];
    __shared__ bf16_t s_q [BN * LDK];
    __shared__ bf16_t s_yy[BN * LDK];
    __shared__ bf16_t s_m2[BN * LDK];

    const int tid  = threadIdx.x;
    const int lane = tid & 63;
    const int wid  = tid >> 6;
    const int quad = lane >> 4;
    const int r16  = lane & 15;
    const int wrow = (wid >> 1) * 64;
    const int wcol = (wid & 1) * 64;
    const int blockRow = blockIdx.y * BM;
    const int blockCol = blockIdx.x * BN;

    floatx4 acc_d[4][4];
    floatx4 acc_c[4][4];
    #pragma unroll
    for (int i = 0; i < 4; i++)
        #pragma unroll
        for (int j = 0; j < 4; j++)
            #pragma unroll
            for (int r = 0; r < 4; r++) { acc_d[i][j][r] = 0.f; acc_c[i][j][r] = 0.f; }

    for (int kc = 0; kc < DDIM / 32; kc++) {
        const int kbase = kc * 32;
        #pragma unroll
        for (int i = 0; i < 4; i++) {
            int idx = tid + 256 * i;
            int row = idx >> 3;
            int c4  = idx & 7;
            const float4 v = *(const float4*)(X + (size_t)(blockRow + row) * DDIM + kbase + c4 * 4);
            bf16x4 vxc, vxx, vp;
            const float xs[4] = {v.x, v.y, v.z, v.w};
            #pragma unroll
            for (int e = 0; e < 4; e++) {
                float x = xs[e];
                bool miss = __builtin_isnan(x);
                float xc = miss ? 0.f : x;
                vxc[e] = (bf16_t)xc;
                vxx[e] = (bf16_t)(xc * xc);
                vp[e]  = miss ? (bf16_t)0.f : (bf16_t)1.f;
            }
            int off = row * LDK + c4 * 4;
            *(bf16x4*)&s_xc[off] = vxc;
            *(bf16x4*)&s_xx[off] = vxx;
            *(bf16x4*)&s_p [off] = vp;
        }
        #pragma unroll
        for (int i = 0; i < 4; i++) {
            int idx = tid + 256 * i;
            int row = idx >> 3;
            int c4  = idx & 7;
            const float4 v = *(const float4*)(Y + (size_t)(blockCol + row) * DDIM + kbase + c4 * 4);
            bf16x4 vq, vyy, vm2;
            const float ys[4] = {v.x, v.y, v.z, v.w};
            #pragma unroll
            for (int e = 0; e < 4; e++) {
                float y = ys[e];
                bool miss = __builtin_isnan(y);
                float yc = miss ? 0.f : y;
                vq[e]  = miss ? (bf16_t)0.f : (bf16_t)1.f;
                vyy[e] = (bf16_t)(yc * yc);
                vm2[e] = (bf16_t)(-2.f * yc);
            }
            int off = row * LDK + c4 * 4;
            *(bf16x4*)&s_q [off] = vq;
            *(bf16x4*)&s_yy[off] = vyy;
            *(bf16x4*)&s_m2[off] = vm2;
        }
        __syncthreads();
        bf16x8 bq[4], byy[4], bm2[4];
        #pragma unroll
        for (int tn = 0; tn < 4; tn++) {
            int off = (wcol + tn * 16 + r16) * LDK + quad * 8;
            bq[tn]  = *(const bf16x8*)&s_q [off];
            byy[tn] = *(const bf16x8*)&s_yy[off];
            bm2[tn] = *(const bf16x8*)&s_m2[off];
        }
        #pragma unroll
        for (int tm = 0; tm < 4; tm++) {
            int off = (wrow + tm * 16 + r16) * LDK + quad * 8;
            bf16x8 axx = *(const bf16x8*)&s_xx[off];
            bf16x8 ap  = *(const bf16x8*)&s_p [off];
            bf16x8 axc = *(const bf16x8*)&s_xc[off];
            #pragma unroll
            for (int tn = 0; tn < 4; tn++) {
                acc_d[tm][tn] = __builtin_amdgcn_mfma_f32_16x16x32_bf16(axx, bq[tn],  acc_d[tm][tn], 0, 0, 0);
                acc_d[tm][tn] = __builtin_amdgcn_mfma_f32_16x16x32_bf16(ap,  byy[tn], acc_d[tm][tn], 0, 0, 0);
                acc_d[tm][tn] = __builtin_amdgcn_mfma_f32_16x16x32_bf16(axc, bm2[tn], acc_d[tm][tn], 0, 0, 0);
                acc_c[tm][tn] = __builtin_amdgcn_mfma_f32_16x16x32_bf16(ap,  bq[tn],  acc_c[tm][tn], 0, 0, 0);
            }
        }
        __syncthreads();
    }
    #pragma unroll
    for (int tm = 0; tm < 4; tm++) {
        #pragma unroll
        for (int tn = 0; tn < 4; tn++) {
            int col = blockCol + wcol + tn * 16 + r16;
            #pragma unroll
            for (int r = 0; r < 4; r++) {
                int row = blockRow + wrow + tm * 16 + quad * 4 + r;
                float d = acc_d[tm][tn][r];
                float c = acc_c[tm][tn][r];
                d = fmaxf(d, 0.f);
                float res = (c < 0.5f) ? __builtin_nanf("")
                                       : __builtin_sqrtf(d * (float)DDIM / c);
                out[(size_t)row * MCOLS + col] = res;
            }
        }
    }
}

extern "C" void kernel_launch(void* const* d_in, const int* in_sizes, int n_in,
                              void* d_out, int out_size, void* d_ws, size_t ws_size,
                              hipStream_t stream) {
    const float* X = (const float*)d_in[0];
    const float* Y = (const float*)d_in[1];
    float* out = (float*)d_out;

    if (ws_size >= WS_NEEDED) {
        char* ws = (char*)d_ws;
        convert_planes_mx<<<dim3(8192), dim3(256), 0, stream>>>(X, Y, ws);
        dim3 grid(MCOLS / BN, NROWS / BM);
        nan_euclid_mx<<<grid, dim3(256), 0, stream>>>(ws, out);
    } else {
        dim3 grid(MCOLS / BN, NROWS / BM);
        nan_euclid_fused<<<grid, dim3(256), 0, stream>>>(X, Y, out);
    }
}

// Round 5
// 166.891 us; speedup vs baseline: 5.3141x; 1.1912x over previous
//
#include <hip/hip_runtime.h>
#include <hip/hip_bf16.h>
#include <stdint.h>

// NaN-masked euclidean distances via MX-scaled all-fp8 MFMA (unity scales).
//   prepass v5: PLANE-SPECIALIZED blocks -- 6 jobs x 1024 blocks; each block
//               writes exactly ONE plane, so each wave emits a single contiguous
//               1KB store stream (R4 lesson: per-wave multi-stream scatter across
//               4MB-apart planes was the prepass cost; inputs re-read 3x from L3).
//               ws layout = EXACT R0 (6 separate 4MB planes, pre-swizzled 16B
//               chunks: phys = logical ^ ((row>>1)&3) within each 64B k-group).
//   main:      EXACT R0 kernel (128x128 tile, 256 thr, 4 waves 2x2, single 48KB
//               LDS buffer, 2 barriers/K-step, 2D grid, NO setprio) -- proven
//               89us, VGPR 104, no spill. R1-R4 lessons: AGPR=128 floor caps at
//               2 waves/SIMD; any VGPR>128 or LDS>80KB loses the hiding TLP;
//               interleaved ws layouts stretch the staging critical path ~2x.
//   d = xx*q + p*yy + xc*m2 ; cnt = p*q  (fp8 0/1 products -> exact)
//   out = sqrt(clip(d,0)*D/max(1,cnt)), NaN where cnt==0.
// Floors: MFMA 29.3us (per-SIMD 68.7cy/inst), LDS reads 31-41us.

typedef __bf16 bf16_t;
typedef __attribute__((ext_vector_type(8))) __bf16 bf16x8;
typedef __attribute__((ext_vector_type(4))) float floatx4;
typedef __attribute__((ext_vector_type(16))) float floatx16;
typedef __attribute__((ext_vector_type(8))) int int32x8;

#define NROWS 4096
#define MCOLS 4096
#define DDIM  1024
#define BM 128
#define BN 128
#define BK 64

// ws layout: 6 fp8 planes x 4 MB (row = 1024 B, pre-swizzled chunks)
#define WS_XX ((uint32_t)0)
#define WS_XC ((uint32_t)(4  << 20))
#define WS_P  ((uint32_t)(8  << 20))
#define WS_YY ((uint32_t)(12 << 20))
#define WS_M2 ((uint32_t)(16 << 20))
#define WS_Q  ((uint32_t)(20 << 20))
#define WS_NEEDED ((size_t)(24 << 20))

// LDS plane bases: 6 planes x 8192 B ([128 rows x 64 B])
#define L_XX 0
#define L_XC 8192
#define L_P  16384
#define L_YY 24576
#define L_M2 32768
#define L_Q  40960

// ---------------- prepass v5: plane-specialized, single write stream per wave ----------------
// 6144 blocks x 256 thr: job = b>>10 (0:XX 1:XC 2:P | 3:YY 4:M2 5:Q), rb = b&1023,
// 4 rows/block, 16 elems/thread. Each wave: 4 float4 loads + one 1KB plane store.
__global__ __launch_bounds__(256)
void convert_planes_mx(const float* __restrict__ X, const float* __restrict__ Y,
                       char* __restrict__ ws) {
    int b = blockIdx.x;
    int job = b >> 10;               // uniform per block
    int rb  = b & 1023;
    bool isX = (job < 3);
    const float* src = isX ? X : Y;
    int row = rb * 4 + (threadIdx.x >> 6);
    int l = threadIdx.x & 63;
    int k0 = l << 4;

    const float4* p = (const float4*)(src + (size_t)row * DDIM + k0);
    float v[16];
    #pragma unroll
    for (int i = 0; i < 4; i++) {
        float4 t = p[i];
        v[4*i+0] = t.x; v[4*i+1] = t.y; v[4*i+2] = t.z; v[4*i+3] = t.w;
    }
    // kind 0: squares (XX/YY); kind 1: value (XC: c, M2: -2c); kind 2: mask (P/Q)
    int kind = (job == 0 || job == 3) ? 0 : (job == 1 || job == 4) ? 1 : 2;
    float f[16];
    #pragma unroll
    for (int i = 0; i < 16; i++) {
        float x = v[i];
        bool miss = __builtin_isnan(x);
        float c = miss ? 0.f : x;
        f[i] = (kind == 0) ? c * c
             : (kind == 1) ? (isX ? c : (-2.f * c))
             :               (miss ? 0.f : 1.f);
    }
    uint32_t d[4];
    #pragma unroll
    for (int i = 0; i < 4; i++) {
        int r = __builtin_amdgcn_cvt_pk_fp8_f32(f[4*i], f[4*i+1], 0, 0);
        r     = __builtin_amdgcn_cvt_pk_fp8_f32(f[4*i+2], f[4*i+3], r, 1);
        d[i] = (uint32_t)r;
    }
    // 16B chunk swizzle inside each 64B k-group: phys = logical ^ ((row>>1)&3)
    uint32_t off8 = (uint32_t)row * 1024u + (uint32_t)(l >> 2) * 64u
                  + (uint32_t)((((l & 3) ^ ((row >> 1) & 3)) << 4));
    uint32_t base = (job == 0) ? WS_XX : (job == 1) ? WS_XC : (job == 2) ? WS_P
                  : (job == 3) ? WS_YY : (job == 4) ? WS_M2 : WS_Q;
    *(uint4*)(ws + base + off8) = make_uint4(d[0], d[1], d[2], d[3]);
}

// ---------------- main MX MFMA kernel (EXACT R0) ----------------
__device__ __forceinline__ int32x8 ld32B(const char* p0, const char* p1) {
    union { int32x8 v; int4 h[2]; } u;
    u.h[0] = *(const int4*)p0;
    u.h[1] = *(const int4*)p1;
    return u.v;
}

__global__ __launch_bounds__(256, 2)
void nan_euclid_mx(const char* __restrict__ ws, float* __restrict__ out) {
    __shared__ __align__(16) char ldsb[49152];

    const int tid = threadIdx.x, lane = tid & 63, wid = tid >> 6;
    const int l31 = lane & 31, kh = lane >> 5;
    const int wrow = (wid >> 1) * 64, wcol = (wid & 1) * 64;
    const int blockRow = blockIdx.y * BM, blockCol = blockIdx.x * BN;

    // staging: 12 global_load_lds (16B) per wave per kc; identity copy (ws pre-swizzled)
    // global chunk id ch in [0,3072): plane = ch>>9 (XX,XC,P,YY,M2,Q), c2 = ch&511,
    // row = c2>>2, cc = c2&3. LDS byte = ch*16.
    uint32_t goff[12];
    #pragma unroll
    for (int t = 0; t < 12; t++) {
        int ch = (wid * 12 + t) * 64 + lane;
        int pl = ch >> 9;
        int c2 = ch & 511;
        int row = c2 >> 2, cc = c2 & 3;
        int rg = (pl < 3 ? blockRow : blockCol) + row;
        uint32_t base = (pl == 0) ? WS_XX : (pl == 1) ? WS_XC : (pl == 2) ? WS_P
                      : (pl == 3) ? WS_YY : (pl == 4) ? WS_M2 : WS_Q;
        goff[t] = base + (uint32_t)rg * 1024u + (uint32_t)(cc << 4);
    }

    // fragment-read LDS offsets (within plane); operand = 32 k-elems at k-half kh
    // logical quarters 2kh, 2kh+1; physical = logical ^ ((m>>1)&3)
    int aoff0[2], aoff1[2], boff0[2], boff1[2];
    #pragma unroll
    for (int tt = 0; tt < 2; tt++) {
        int m = wrow + tt * 32 + l31;
        int sw = (m >> 1) & 3;
        aoff0[tt] = m * 64 + (((kh * 2)     ^ sw) << 4);
        aoff1[tt] = m * 64 + (((kh * 2 + 1) ^ sw) << 4);
        int n = wcol + tt * 32 + l31;
        int swn = (n >> 1) & 3;
        boff0[tt] = n * 64 + (((kh * 2)     ^ swn) << 4);
        boff1[tt] = n * 64 + (((kh * 2 + 1) ^ swn) << 4);
    }

    floatx16 acc_d[2][2], acc_c[2][2];
    #pragma unroll
    for (int i = 0; i < 2; i++)
        #pragma unroll
        for (int j = 0; j < 2; j++)
            #pragma unroll
            for (int r = 0; r < 16; r++) { acc_d[i][j][r] = 0.f; acc_c[i][j][r] = 0.f; }

    for (int kc = 0; kc < DDIM / BK; kc++) {
        #pragma unroll
        for (int t = 0; t < 12; t++) {
            __builtin_amdgcn_global_load_lds(
                (const __attribute__((address_space(1))) void*)(ws + goff[t] + kc * 64u),
                (__attribute__((address_space(3))) void*)(ldsb + (uint32_t)((wid * 12 + t) * 1024)),
                16, 0, 0);
        }
        __syncthreads();

        int32x8 axx[2], axc[2], ap[2], byy[2], bm2[2], bq[2];
        #pragma unroll
        for (int tt = 0; tt < 2; tt++) {
            axx[tt] = ld32B(ldsb + L_XX + aoff0[tt], ldsb + L_XX + aoff1[tt]);
            axc[tt] = ld32B(ldsb + L_XC + aoff0[tt], ldsb + L_XC + aoff1[tt]);
            ap [tt] = ld32B(ldsb + L_P  + aoff0[tt], ldsb + L_P  + aoff1[tt]);
            byy[tt] = ld32B(ldsb + L_YY + boff0[tt], ldsb + L_YY + boff1[tt]);
            bm2[tt] = ld32B(ldsb + L_M2 + boff0[tt], ldsb + L_M2 + boff1[tt]);
            bq [tt] = ld32B(ldsb + L_Q  + boff0[tt], ldsb + L_Q  + boff1[tt]);
        }

        // chain-major order: dependency distance 4 insts per accumulator
        #pragma unroll
        for (int tm = 0; tm < 2; tm++)
            #pragma unroll
            for (int tn = 0; tn < 2; tn++)
                acc_d[tm][tn] = __builtin_amdgcn_mfma_scale_f32_32x32x64_f8f6f4(
                    axx[tm], bq[tn], acc_d[tm][tn], 0, 0, 0, 0x7f7f7f7f, 0, 0x7f7f7f7f);
        #pragma unroll
        for (int tm = 0; tm < 2; tm++)
            #pragma unroll
            for (int tn = 0; tn < 2; tn++)
                acc_d[tm][tn] = __builtin_amdgcn_mfma_scale_f32_32x32x64_f8f6f4(
                    ap[tm], byy[tn], acc_d[tm][tn], 0, 0, 0, 0x7f7f7f7f, 0, 0x7f7f7f7f);
        #pragma unroll
        for (int tm = 0; tm < 2; tm++)
            #pragma unroll
            for (int tn = 0; tn < 2; tn++)
                acc_d[tm][tn] = __builtin_amdgcn_mfma_scale_f32_32x32x64_f8f6f4(
                    axc[tm], bm2[tn], acc_d[tm][tn], 0, 0, 0, 0x7f7f7f7f, 0, 0x7f7f7f7f);
        #pragma unroll
        for (int tm = 0; tm < 2; tm++)
            #pragma unroll
            for (int tn = 0; tn < 2; tn++)
                acc_c[tm][tn] = __builtin_amdgcn_mfma_scale_f32_32x32x64_f8f6f4(
                    ap[tm], bq[tn], acc_c[tm][tn], 0, 0, 0, 0x7f7f7f7f, 0, 0x7f7f7f7f);

        __syncthreads();
    }

    // epilogue; 32x32 C/D layout (m74/m101): col = lane&31, row = (reg&3)+8*(reg>>2)+4*(lane>>5)
    #pragma unroll
    for (int tm = 0; tm < 2; tm++) {
        #pragma unroll
        for (int tn = 0; tn < 2; tn++) {
            int col = blockCol + wcol + tn * 32 + l31;
            #pragma unroll
            for (int r = 0; r < 16; r++) {
                int rowl = (r & 3) + 8 * (r >> 2) + 4 * kh;
                int row = blockRow + wrow + tm * 32 + rowl;
                float d = fmaxf(acc_d[tm][tn][r], 0.f);
                float c = acc_c[tm][tn][r];
                float res = (c < 0.5f) ? __builtin_nanf("")
                                       : __builtin_sqrtf(d * (float)DDIM / c);
                out[(size_t)row * MCOLS + col] = res;
            }
        }
    }
}

// ---------------- fallback: fused single-kernel bf16 (if ws too small) ----------------
#define LDK 40
__global__ __launch_bounds__(256, 2)
void nan_euclid_fused(const float* __restrict__ X, const float* __restrict__ Y,
                      float* __restrict__ out) {
    typedef __attribute__((ext_vector_type(4))) __bf16 bf16x4;
    __shared__ bf16_t s_xx[BM * LDK];
    __shared__ bf16_t s_p [BM * LDK];
    __shared__ bf16_t s_xc[BM * LDK];
    __shared__ bf16_t s_q [BN * LDK];
    __shared__ bf16_t s_yy[BN * LDK];
    __shared__ bf16_t s_m2[BN * LDK];

    const int tid  = threadIdx.x;
    const int lane = tid & 63;
    const int wid  = tid >> 6;
    const int quad = lane >> 4;
    const int r16  = lane & 15;
    const int wrow = (wid >> 1) * 64;
    const int wcol = (wid & 1) * 64;
    const int blockRow = blockIdx.y * BM;
    const int blockCol = blockIdx.x * BN;

    floatx4 acc_d[4][4];
    floatx4 acc_c[4][4];
    #pragma unroll
    for (int i = 0; i < 4; i++)
        #pragma unroll
        for (int j = 0; j < 4; j++)
            #pragma unroll
            for (int r = 0; r < 4; r++) { acc_d[i][j][r] = 0.f; acc_c[i][j][r] = 0.f; }

    for (int kc = 0; kc < DDIM / 32; kc++) {
        const int kbase = kc * 32;
        #pragma unroll
        for (int i = 0; i < 4; i++) {
            int idx = tid + 256 * i;
            int row = idx >> 3;
            int c4  = idx & 7;
            const float4 v = *(const float4*)(X + (size_t)(blockRow + row) * DDIM + kbase + c4 * 4);
            bf16x4 vxc, vxx, vp;
            const float xs[4] = {v.x, v.y, v.z, v.w};
            #pragma unroll
            for (int e = 0; e < 4; e++) {
                float x = xs[e];
                bool miss = __builtin_isnan(x);
                float xc = miss ? 0.f : x;
                vxc[e] = (bf16_t)xc;
                vxx[e] = (bf16_t)(xc * xc);
                vp[e]  = miss ? (bf16_t)0.f : (bf16_t)1.f;
            }
            int off = row * LDK + c4 * 4;
            *(bf16x4*)&s_xc[off] = vxc;
            *(bf16x4*)&s_xx[off] = vxx;
            *(bf16x4*)&s_p [off] = vp;
        }
        #pragma unroll
        for (int i = 0; i < 4; i++) {
            int idx = tid + 256 * i;
            int row = idx >> 3;
            int c4  = idx & 7;
            const float4 v = *(const float4*)(Y + (size_t)(blockCol + row) * DDIM + kbase + c4 * 4);
            bf16x4 vq, vyy, vm2;
            const float ys[4] = {v.x, v.y, v.z, v.w};
            #pragma unroll
            for (int e = 0; e < 4; e++) {
                float y = ys[e];
                bool miss = __builtin_isnan(y);
                float yc = miss ? 0.f : y;
                vq[e]  = miss ? (bf16_t)0.f : (bf16_t)1.f;
                vyy[e] = (bf16_t)(yc * yc);
                vm2[e] = (bf16_t)(-2.f * yc);
            }
            int off = row * LDK + c4 * 4;
            *(bf16x4*)&s_q [off] = vq;
            *(bf16x4*)&s_yy[off] = vyy;
            *(bf16x4*)&s_m2[off] = vm2;
        }
        __syncthreads();
        bf16x8 bq[4], byy[4], bm2[4];
        #pragma unroll
        for (int tn = 0; tn < 4; tn++) {
            int off = (wcol + tn * 16 + r16) * LDK + quad * 8;
            bq[tn]  = *(const bf16x8*)&s_q [off];
            byy[tn] = *(const bf16x8*)&s_yy[off];
            bm2[tn] = *(const bf16x8*)&s_m2[off];
        }
        #pragma unroll
        for (int tm = 0; tm < 4; tm++) {
            int off = (wrow + tm * 16 + r16) * LDK + quad * 8;
            bf16x8 axx = *(const bf16x8*)&s_xx[off];
            bf16x8 ap  = *(const bf16x8*)&s_p [off];
            bf16x8 axc = *(const bf16x8*)&s_xc[off];
            #pragma unroll
            for (int tn = 0; tn < 4; tn++) {
                acc_d[tm][tn] = __builtin_amdgcn_mfma_f32_16x16x32_bf16(axx, bq[tn],  acc_d[tm][tn], 0, 0, 0);
                acc_d[tm][tn] = __builtin_amdgcn_mfma_f32_16x16x32_bf16(ap,  byy[tn], acc_d[tm][tn], 0, 0, 0);
                acc_d[tm][tn] = __builtin_amdgcn_mfma_f32_16x16x32_bf16(axc, bm2[tn], acc_d[tm][tn], 0, 0, 0);
                acc_c[tm][tn] = __builtin_amdgcn_mfma_f32_16x16x32_bf16(ap,  bq[tn],  acc_c[tm][tn], 0, 0, 0);
            }
        }
        __syncthreads();
    }
    #pragma unroll
    for (int tm = 0; tm < 4; tm++) {
        #pragma unroll
        for (int tn = 0; tn < 4; tn++) {
            int col = blockCol + wcol + tn * 16 + r16;
            #pragma unroll
            for (int r = 0; r < 4; r++) {
                int row = blockRow + wrow + tm * 16 + quad * 4 + r;
                float d = acc_d[tm][tn][r];
                float c = acc_c[tm][tn][r];
                d = fmaxf(d, 0.f);
                float res = (c < 0.5f) ? __builtin_nanf("")
                                       : __builtin_sqrtf(d * (float)DDIM / c);
                out[(size_t)row * MCOLS + col] = res;
            }
        }
    }
}

extern "C" void kernel_launch(void* const* d_in, const int* in_sizes, int n_in,
                              void* d_out, int out_size, void* d_ws, size_t ws_size,
                              hipStream_t stream) {
    const float* X = (const float*)d_in[0];
    const float* Y = (const float*)d_in[1];
    float* out = (float*)d_out;

    if (ws_size >= WS_NEEDED) {
        char* ws = (char*)d_ws;
        convert_planes_mx<<<dim3(6144), dim3(256), 0, stream>>>(X, Y, ws);
        dim3 grid(MCOLS / BN, NROWS / BM);
        nan_euclid_mx<<<grid, dim3(256), 0, stream>>>(ws, out);
    } else {
        dim3 grid(MCOLS / BN, NROWS / BM);
        nan_euclid_fused<<<grid, dim3(256), 0, stream>>>(X, Y, out);
    }
}